// Round 9
// baseline (102.088 us; speedup 1.0000x reference)
//
#include <hip/hip_runtime.h>

typedef _Float16 half8  __attribute__((ext_vector_type(8)));
typedef __fp16   fp16x2 __attribute__((ext_vector_type(2)));   // cvt_pkrtz native type
typedef float    floatx4 __attribute__((ext_vector_type(4)));
typedef float    f4a __attribute__((ext_vector_type(4), aligned(4)));  // 4B-aligned float4 load

#define IMG_H 64
#define IMG_W 64
#define TH 16             // rows per strip-block (two 8-row wave-strips); full image width
#define INW 72            // staged cols: img cols -4 .. 67 (zeros outside 0..63)
#define H1W 66            // h1 cols 0..65 = img cols -1..64 (cols 0 and 65 always zero)
#define H1H 17            // h1 rows 0..16 = img rows ty0-1 .. ty0+15
#define PLDW (H1H*H1W*2)  // dwords per h1 plane = 2244
#define CP 1440           // f16 elems per staged copy (20 rows x 72)
#define CPM1 1439         // reader: elem off = c*CPM1 + 4 + S + row*INW
#define S16N (4*CP + 4)   // +4: copy-3 tail spill pad

__device__ __forceinline__ unsigned pk2u(float a, float b) {
    fp16x2 h = __builtin_amdgcn_cvt_pkrtz(a, b);
    return __builtin_bit_cast(unsigned, h);
}

__global__ __launch_bounds__(512, 8) void pixelcnn_mfma14(
    const float* __restrict__ x,
    const float* __restrict__ w1, const float* __restrict__ b1,
    const float* __restrict__ w2, const float* __restrict__ b2,
    const float* __restrict__ w3, const float* __restrict__ b3,
    float* __restrict__ out)
{
    // LDS: 11528 + 1536 + 17952 = 31016 B -> 4 blocks/CU x 8 waves = 32 waves/CU (full)
    __shared__ __align__(16) _Float16      s16[S16N];      // input strip f16, 4 shifted copies
    __shared__ __align__(16) unsigned char s_w2t8[16 * 96];// [ch][k] fp8 e4m3, k=tap*16+ic
    __shared__ __align__(16) unsigned      s_h1[2 * PLDW]; // fp8 h1: [plane][px][8ch] 8B/px/plane

    const int t    = threadIdx.x;
    const int lane = t & 63;
    const int wave = t >> 6;
    const int n    = lane & 15;   // MFMA: weight-row ch field & B-col pixel field
    const int quad = lane >> 4;   // MFMA k-slice group / D-row quad
    const int s    = wave >> 2;   // strip (0: rows ty0..+7, 1: rows ty0+8..+15)
    const int x0q  = wave & 3;    // col quarter
    const int ty0  = blockIdx.x * TH;
    const int img0 = blockIdx.y * 2;          // two images per block

    const float* xim0 = x + img0 * (IMG_H * IMG_W);
    const float* xim1 = xim0 + IMG_H * IMG_W;
    float* outb = out + img0 * (IMG_H * IMG_W);

    // ------- Per-lane weights/biases DIRECT from global (L2-hot, 3KB total) -------
    // A-frag: w1[n][kr=quad][kc=j], j<7 (quad<3) / j<3 (quad==3); RTE casts match old path.
    const float* wr = w1 + n * 49 + quad * 7;
    f4a wlo = *(const f4a*)wr;          // kc 0..3   (4B-aligned load)
    f4a whi = *(const f4a*)(wr + 3);    // kc 3..6   (max idx 762 < 784: in-bounds)
    const floatx4 bias1 = *(const floatx4*)(b1 + quad * 4);
    const floatx4 bias2 = *(const floatx4*)(b2 + quad * 4);
    const floatx4 w3q   = *(const floatx4*)(w3 + quad * 4);
    const float   bias3 = b3[0];
    half8 af;
    {
        bool q3 = (quad == 3);
        af[0] = (_Float16)wlo[0];
        af[1] = (_Float16)wlo[1];
        af[2] = (_Float16)wlo[2];
        af[3] = (_Float16)(q3 ? 0.f : wlo[3]);
        af[4] = (_Float16)(q3 ? 0.f : whi[1]);
        af[5] = (_Float16)(q3 ? 0.f : whi[2]);
        af[6] = (_Float16)(q3 ? 0.f : whi[3]);
        af[7] = (_Float16)0.f;
    }

    // ------- Hoisted img-invariant address constants -------
    // phase 1: lane owns img col px (fixed), rows advance by INW.
    const int px_ = x0q * 16 + n;                 // img col, 0..63
    const int S_  = px_ + 1;                      // staged read start col
    const _Float16* ap0 = &s16[(S_ & 3) * CPM1 + 4 + S_ + (s * 8 + quad) * INW];
    const unsigned wd0 = (unsigned)((quad >> 1) * PLDW + ((s * 8) * H1W + S_) * 2 + (quad & 1));
    const bool top = (ty0 == 0) && (s == 0);
    // phase 2: taps f0 -> {(-1,-1),(-1,0)}, f1 -> {(-1,1),(0,-1)}, f2 -> {(0,0), pad(A=0)}
    const int tqh = quad >> 1, plane = quad & 1;
    const int E0 = (s * 8 + 1) * H1W + x0q * 16 + n + 1;  // lane pixel, out row ty0+s*8 (k=0)
    const char* h1b = (const char*)s_h1 + plane * (PLDW * 4);
    const char* a0 = h1b + (E0 - H1W - 1 + tqh) * 8;
    const char* a1 = h1b + (E0 + (tqh ? -1 : -(H1W - 1))) * 8;
    const char* a2 = h1b + E0 * 8;                        // tqh=1 reads real px (zero A-side)

    // ------- Stage: 20-row input strip as f16 x4 shifted copies -------
    // Copy c stores col X of row r at elem c*CP + 4 + r*INW + (X - c); reader uses
    // E = c*CPM1 + 4 + S + row*INW (E ≡ 0 mod 4 since S ≡ c mod 4). OOB loads -> zeros.
    auto stage = [&](const float* xim) {
        if (t < 360) {
            int r = t / 18, c4 = (t - r * 18) * 4;
            int gy = ty0 - 4 + r;
            int gx0 = c4 - 4;                       // img col, multiple of 4
            float4 v  = {0.f, 0.f, 0.f, 0.f};
            float4 v2 = {0.f, 0.f, 0.f, 0.f};
            if ((unsigned)gy < IMG_H) {
                const float* rp = xim + gy * IMG_W;
                if ((unsigned)gx0 < IMG_W)       v  = *(const float4*)(rp + gx0);
                if ((unsigned)(gx0 + 4) < IMG_W) v2 = *(const float4*)(rp + gx0 + 4);
            }
            unsigned a0w = pk2u(v.x,  v.y),  a1w = pk2u(v.z,  v.w);
            unsigned a2w = pk2u(v2.x, v2.y), a3w = pk2u(v2.z, v2.w);
            unsigned m10 = (a0w >> 16) | (a1w << 16);   // elems 1,2
            unsigned m21 = (a1w >> 16) | (a2w << 16);   // elems 3,4
            unsigned m32 = (a2w >> 16) | (a3w << 16);   // elems 5,6
            int lin = r * INW + c4;
            *(uint2*)&s16[0*CP + 4 + lin] = uint2{a0w, a1w};  // cols c4..c4+3
            *(uint2*)&s16[1*CP + 4 + lin] = uint2{m10, m21};  // cols c4+1..c4+4
            *(uint2*)&s16[2*CP + 4 + lin] = uint2{a1w, a2w};  // cols c4+2..c4+5
            *(uint2*)&s16[3*CP + 4 + lin] = uint2{m21, m32};  // cols c4+3..c4+6
        }
    };

    // ------- Phase 1: L1 7x7 via f16 MFMA; fixed column per lane, rows advance -------
    // Wave (s, x0q): h1 rows s*8 .. s*8+8. Strip 1 skips i=0 (row 8 owned by strip 0).
    auto phase1 = [&]() {
#pragma unroll
        for (int i = 0; i < 9; ++i) {             // h1 row s*8+i = img row ty0-1+s*8+i
            if (i == 0 && s != 0) continue;
            const _Float16* ap = ap0 + i * INW;
            uint2 lo = *(const uint2*)ap;         // staged cols S..S+3 (8B aligned)
            uint2 hi = *(const uint2*)(ap + 4);   // staged cols S+4..S+7
            uint4 bu; bu.x = lo.x; bu.y = lo.y; bu.z = hi.x; bu.w = hi.y;
            half8 b = __builtin_bit_cast(half8, bu);
            floatx4 acc = bias1;
            acc = __builtin_amdgcn_mfma_f32_16x16x32_f16(af, b, acc, 0, 0, 0);
            // D: row = ch = quad*4+r, col = px = n -> 4 ch as 4 fp8 bytes = one b32
            int d = __builtin_amdgcn_cvt_pk_fp8_f32(fmaxf(acc[0], 0.f), fmaxf(acc[1], 0.f), 0, false);
            d = __builtin_amdgcn_cvt_pk_fp8_f32(fmaxf(acc[2], 0.f), fmaxf(acc[3], 0.f), d, true);
            unsigned dv = (unsigned)d;
            if (i == 0 && top) dv = 0u;           // h1 row 0 = img row -1 for top block
            s_h1[wd0 + i * (H1W * 2)] = dv;
        }
    };

    // ------- Stage img0 + per-block one-time prep -------
    stage(xim0);
    if (t >= 360 && t < 394) {
        // zero h1 border cols 0 and 65 (img cols -1, 64 -> always out of image);
        // phase 1 never writes these cells (writes cols 1..64 only) -> zero ONCE per block.
        int idx = t - 360;                       // 17 rows x {0,65}
        int cell = (idx >> 1) * H1W + ((idx & 1) ? 65 : 0);
        *(uint2*)&s_h1[cell * 2]        = uint2{0u, 0u};
        *(uint2*)&s_h1[PLDW + cell * 2] = uint2{0u, 0u};
    }
    if (t >= 256) {
        // w2t8: k = tap*16 + ic, fp8 e4m3 -- 256 threads = 16 ch x 16 ic; once per block
        int ch = (t >> 4) & 15, l = t & 15;
        const float* w2cl = w2 + (ch * 16 + l) * 9;
#pragma unroll
        for (int j = 0; j < 6; ++j) {
            float v = (j < 5) ? w2cl[j] : 0.f;
            unsigned q8 = (unsigned)__builtin_amdgcn_cvt_pk_fp8_f32(v, 0.f, 0, false);
            s_w2t8[ch * 96 + j * 16 + l] = (unsigned char)(q8 & 0xff);
        }
    }
    __syncthreads();

    // w2 fragments: once per block (valid from here on; s_w2t8 never rewritten)
    const long w2f0 = *(const long*)&s_w2t8[n * 96 +  0 + quad * 8];
    const long w2f1 = *(const long*)&s_w2t8[n * 96 + 32 + quad * 8];
    const long w2f2 = *(const long*)&s_w2t8[n * 96 + 64 + quad * 8];

    // ------- Phase 2: L2 3x3 via fp8 MFMA + fused relu/w3-dot/sigmoid/store -------
    // Reduction: proven shfl_xor(16)/shfl_xor(32) form (round-4 verified). The
    // permlane32_swap variant was reverted: its half-swap direction is unverified on
    // this HW and the round-5 failure signature (rows 0<->2,1<->3 pair-swap, absmax
    // 0.07) matches the reversed-direction hypothesis.
    auto phase2 = [&](float* outim) {
        // lane (n, quad) stores row ty0 + s*8 + g*4 + quad, col x0q*16 + n
        float* sbase = outim + (ty0 + s * 8 + quad) * IMG_W + x0q * 16 + n;
#pragma unroll
        for (int g = 0; g < 2; ++g) {                    // 2 groups of 4 rows
            float sv0, sv1, sv2, sv3;
#pragma unroll
            for (int q = 0; q < 4; ++q) {                // k = g*4+q; row step = 66 px = 528 B
                const int k = g * 4 + q;
                floatx4 acc = bias2;
                acc = __builtin_amdgcn_mfma_f32_16x16x32_fp8_fp8(w2f0, *(const long*)(a0 + k * 528), acc, 0, 0, 0);
                acc = __builtin_amdgcn_mfma_f32_16x16x32_fp8_fp8(w2f1, *(const long*)(a1 + k * 528), acc, 0, 0, 0);
                acc = __builtin_amdgcn_mfma_f32_16x16x32_fp8_fp8(w2f2, *(const long*)(a2 + k * 528), acc, 0, 0, 0);
                float sacc = fmaxf(acc[0], 0.f) * w3q[0];
                sacc = fmaf(fmaxf(acc[1], 0.f), w3q[1], sacc);
                sacc = fmaf(fmaxf(acc[2], 0.f), w3q[2], sacc);
                sacc = fmaf(fmaxf(acc[3], 0.f), w3q[3], sacc);
                sacc += __shfl_xor(sacc, 16);
                sacc += __shfl_xor(sacc, 32);            // full 16-ch sum, replicated in all quads
                if      (q == 0) sv0 = sacc;
                else if (q == 1) sv1 = sacc;
                else if (q == 2) sv2 = sacc;
                else             sv3 = sacc;
            }
            // each lane picks the k matching its quad -> full-wave sigmoid + unmasked store
            float t01 = (quad & 1) ? sv1 : sv0;
            float t23 = (quad & 1) ? sv3 : sv2;
            float v   = (quad & 2) ? t23 : t01;
            float r = __builtin_amdgcn_rcpf(1.f + __expf(-(v + bias3)));
            *(float*)((char*)sbase + g * 1024) = r;      // +4 rows per group
        }
    };

    // ------- Pipelined 2-image schedule -------
    phase1();                 // img0: s16 -> s_h1
    __syncthreads();
    stage(xim1);              // img1 s16 overwrite (phase1 img0 done reading; disjoint from s_h1)
    phase2(outb);             // img0: s_h1 -> out
    __syncthreads();          // stage(img1) complete + phase2 done reading s_h1
    phase1();                 // img1
    __syncthreads();
    phase2(outb + IMG_H * IMG_W);
}

extern "C" void kernel_launch(void* const* d_in, const int* in_sizes, int n_in,
                              void* d_out, int out_size, void* d_ws, size_t ws_size,
                              hipStream_t stream) {
    const float* x  = (const float*)d_in[0];
    const float* w1 = (const float*)d_in[1];
    const float* b1 = (const float*)d_in[2];
    const float* w2 = (const float*)d_in[3];
    const float* b2 = (const float*)d_in[4];
    const float* w3 = (const float*)d_in[5];
    const float* b3 = (const float*)d_in[6];
    float* out = (float*)d_out;

    dim3 grid(4, 512);    // 4 16-row strips x 512 image-pairs
    dim3 block(512);
    hipLaunchKernelGGL(pixelcnn_mfma14, grid, block, 0, stream,
                       x, w1, b1, w2, b2, w3, b3, out);
}

// Round 11
// 101.611 us; speedup vs baseline: 1.0047x; 1.0047x over previous
//
#include <hip/hip_runtime.h>

typedef _Float16 half8  __attribute__((ext_vector_type(8)));
typedef __fp16   fp16x2 __attribute__((ext_vector_type(2)));   // cvt_pkrtz native type
typedef float    floatx4 __attribute__((ext_vector_type(4)));
typedef float    f4a __attribute__((ext_vector_type(4), aligned(4)));  // 4B-aligned float4 load

#define IMG_H 64
#define IMG_W 64
#define TH 16             // rows per block (two 8-row strips); full image width
#define INW 72            // staged cols: img cols -4 .. 67 (zeros outside 0..63)
#define H1W 66            // h1 cols 0..65 = img cols -1..64 (cols 0 and 65 always zero)
#define H1H 17            // h1 rows 0..16 = img rows ty0-1 .. ty0+15
#define PLDW (H1H*H1W*2)  // dwords per h1 plane = 2244
#define CP 1440           // f16 elems per staged copy (20 rows x 72)
#define CPM1 1439         // reader: elem off = c*CPM1 + 4 + S + row*INW
#define S16N (4*CP + 4)   // +4: copy-3 tail spill pad

__device__ __forceinline__ unsigned pk2u(float a, float b) {
    fp16x2 h = __builtin_amdgcn_cvt_pkrtz(a, b);
    return __builtin_bit_cast(unsigned, h);
}

__global__ __launch_bounds__(512, 8) void pixelcnn_mfma16(
    const float* __restrict__ x,
    const float* __restrict__ w1, const float* __restrict__ b1,
    const float* __restrict__ w2, const float* __restrict__ b2,
    const float* __restrict__ w3, const float* __restrict__ b3,
    float* __restrict__ out)
{
    // LDS: 11528 + 1536 + 17952 = 31016 B -> 4 blocks/CU x 8 waves = 32 waves/CU (full)
    __shared__ __align__(16) _Float16      s16[S16N];      // input strip f16, 4 shifted copies
    __shared__ __align__(16) unsigned char s_w2t8[16 * 96];// [ch][k] fp8 e4m3, k=tap*16+ic
    __shared__ __align__(16) unsigned      s_h1[2 * PLDW]; // fp8 h1: [plane][px][8ch] 8B/px/plane

    const int t    = threadIdx.x;
    const int lane = t & 63;
    const int wave = t >> 6;
    const int n    = lane & 15;   // MFMA: weight-row ch field & B-col pixel field
    const int quad = lane >> 4;   // MFMA k-slice group / D-row quad
    const int s    = wave >> 2;   // strip (0: rows ty0..+7, 1: rows ty0+8..+15)
    const int x0q  = wave & 3;    // col quarter
    const int img  = blockIdx.y;
    const int ty0  = blockIdx.x * TH;

    const float* xim = x + img * (IMG_H * IMG_W);

    // ------- Per-lane weights/biases DIRECT from global (L2-hot, 3KB total) -------
    // A-frag: w1[n][kr=quad][kc=j], j<7 (quad<3) / j<3 (quad==3); RTE casts match old path.
    const float* wr = w1 + n * 49 + quad * 7;
    f4a wlo = *(const f4a*)wr;          // kc 0..3   (4B-aligned load)
    f4a whi = *(const f4a*)(wr + 3);    // kc 3..6   (max idx 762 < 784: in-bounds)
    const floatx4 bias1 = *(const floatx4*)(b1 + quad * 4);
    const floatx4 bias2 = *(const floatx4*)(b2 + quad * 4);
    const floatx4 w3q   = *(const floatx4*)(w3 + quad * 4);
    const float   bias3 = b3[0];
    half8 af;
    {
        bool q3 = (quad == 3);
        af[0] = (_Float16)wlo[0];
        af[1] = (_Float16)wlo[1];
        af[2] = (_Float16)wlo[2];
        af[3] = (_Float16)(q3 ? 0.f : wlo[3]);
        af[4] = (_Float16)(q3 ? 0.f : whi[1]);
        af[5] = (_Float16)(q3 ? 0.f : whi[2]);
        af[6] = (_Float16)(q3 ? 0.f : whi[3]);
        af[7] = (_Float16)0.f;
    }

    // ------- Phase 0 prologue: disjoint thread groups (critical-path balanced) -------
    // t <  360 : stage input strip (4 shifted f16 copies)
    // t 360-383: zero h1 border cols 0/65 (2 cells/thread, 34 cells total)
    // t >= 384 : w2 -> fp8 LDS transpose, ic-paired (128 threads)
    if (t < 360) {
        // Copy c stores col X of row r at elem c*CP + 4 + r*INW + (X - c); reader uses
        // E = c*CPM1 + 4 + S + row*INW (E ≡ 0 mod 4 since S ≡ c mod 4). OOB loads -> zeros.
        int r = t / 18, c4 = (t - r * 18) * 4;
        int gy = ty0 - 4 + r;
        int gx0 = c4 - 4;                       // img col, multiple of 4
        float4 v  = {0.f, 0.f, 0.f, 0.f};
        float4 v2 = {0.f, 0.f, 0.f, 0.f};
        if ((unsigned)gy < IMG_H) {
            const float* rp = xim + gy * IMG_W;
            if ((unsigned)gx0 < IMG_W)       v  = *(const float4*)(rp + gx0);
            if ((unsigned)(gx0 + 4) < IMG_W) v2 = *(const float4*)(rp + gx0 + 4);
        }
        unsigned a0 = pk2u(v.x,  v.y),  a1 = pk2u(v.z,  v.w);
        unsigned a2 = pk2u(v2.x, v2.y), a3 = pk2u(v2.z, v2.w);
        unsigned m10 = __builtin_amdgcn_alignbit(a1, a0, 16);   // elems 1,2
        unsigned m21 = __builtin_amdgcn_alignbit(a2, a1, 16);   // elems 3,4
        unsigned m32 = __builtin_amdgcn_alignbit(a3, a2, 16);   // elems 5,6
        int lin = r * INW + c4;
        *(uint2*)&s16[0*CP + 4 + lin] = uint2{a0,  a1 };  // cols c4..c4+3
        *(uint2*)&s16[1*CP + 4 + lin] = uint2{m10, m21};  // cols c4+1..c4+4
        *(uint2*)&s16[2*CP + 4 + lin] = uint2{a1,  a2 };  // cols c4+2..c4+5
        *(uint2*)&s16[3*CP + 4 + lin] = uint2{m21, m32};  // cols c4+3..c4+6
    } else if (t < 384) {
        // zero h1 border cols 0 and 65 (img cols -1, 64 -> always out of image);
        // phase 1 never writes these cells, phase 2 reads them. 17 rows x {0,65} = 34 cells.
        int idx = t - 360;                       // cells idx and idx+24
        int cell = (idx >> 1) * H1W + ((idx & 1) ? 65 : 0);
        *(uint2*)&s_h1[cell * 2]        = uint2{0u, 0u};
        *(uint2*)&s_h1[PLDW + cell * 2] = uint2{0u, 0u};
        if (idx < 10) {
            int i2 = idx + 24;
            int cell2 = (i2 >> 1) * H1W + ((i2 & 1) ? 65 : 0);
            *(uint2*)&s_h1[cell2 * 2]        = uint2{0u, 0u};
            *(uint2*)&s_h1[PLDW + cell2 * 2] = uint2{0u, 0u};
        }
    } else {
        // w2t8: k = tap*16 + ic, fp8 e4m3 -- 128 threads = 16 ch x 8 ic-pairs.
        // cvt_pk_fp8 packs both ics of the pair -> u16 store (byte0 = ic0, byte1 = ic1).
        int ch = (t - 384) >> 3, l2 = (t - 384) & 7;
        const float* r0 = w2 + (ch * 16 + 2 * l2) * 9;
        const float* r1 = r0 + 9;
#pragma unroll
        for (int j = 0; j < 6; ++j) {
            float v0 = (j < 5) ? r0[j] : 0.f;
            float v1 = (j < 5) ? r1[j] : 0.f;
            unsigned q8 = (unsigned)__builtin_amdgcn_cvt_pk_fp8_f32(v0, v1, 0, false);
            *(unsigned short*)&s_w2t8[ch * 96 + j * 16 + 2 * l2] = (unsigned short)(q8 & 0xffff);
        }
    }
    __syncthreads();

    // ------- Phase 1: L1 7x7 via f16 MFMA; fixed column per lane, rows advance -------
    // Wave (s, x0q): h1 rows s*8 .. s*8+8. Strip 1 skips i=0 (row 8 owned by strip 0).
    {
        const int px = x0q * 16 + n;              // img col, 0..63
        const int S  = px + 1;                    // staged read start col
        const int c  = S & 3;                     // copy index: fixed per lane
        const _Float16* ap0 = &s16[c * CPM1 + 4 + S + (s * 8 + quad) * INW];
        const unsigned wd0 = (unsigned)((quad >> 1) * PLDW + ((s * 8) * H1W + S) * 2 + (quad & 1));
        const bool top = (ty0 == 0) && (s == 0);

#pragma unroll
        for (int i = 0; i < 9; ++i) {             // h1 row s*8+i = img row ty0-1+s*8+i
            if (i == 0 && s != 0) continue;       // row 8 owned by strip 0
            const _Float16* ap = ap0 + i * INW;
            uint2 lo = *(const uint2*)ap;         // staged cols S..S+3 (8B aligned)
            uint2 hi = *(const uint2*)(ap + 4);   // staged cols S+4..S+7
            uint4 bu; bu.x = lo.x; bu.y = lo.y; bu.z = hi.x; bu.w = hi.y;
            half8 b = __builtin_bit_cast(half8, bu);
            floatx4 acc = bias1;
            acc = __builtin_amdgcn_mfma_f32_16x16x32_f16(af, b, acc, 0, 0, 0);
            // D: row = ch = quad*4+r, col = px = n -> 4 ch as 4 fp8 bytes = one b32
            int d = __builtin_amdgcn_cvt_pk_fp8_f32(fmaxf(acc[0], 0.f), fmaxf(acc[1], 0.f), 0, false);
            d = __builtin_amdgcn_cvt_pk_fp8_f32(fmaxf(acc[2], 0.f), fmaxf(acc[3], 0.f), d, true);
            unsigned dv = (unsigned)d;
            if (i == 0 && top) dv = 0u;           // h1 row 0 = img row -1 for top block
            s_h1[wd0 + i * (H1W * 2)] = dv;
        }
    }
    __syncthreads();

    // ------- Phase 2: L2 3x3 via fp8 MFMA + fused relu/w3-dot/sigmoid/store -------
    // Reduction: proven shfl_xor(16)/shfl_xor(32) form (round-4 verified).
    {
        const long w2f0 = *(const long*)&s_w2t8[n * 96 +  0 + quad * 8];
        const long w2f1 = *(const long*)&s_w2t8[n * 96 + 32 + quad * 8];
        const long w2f2 = *(const long*)&s_w2t8[n * 96 + 64 + quad * 8];
        const int x0 = x0q * 16;
        const int tqh = quad >> 1, plane = quad & 1;
        const int E0 = (s * 8 + 1) * H1W + x0 + n + 1;   // lane pixel, out row ty0+s*8 (k=0)
        // taps: f0 -> {(-1,-1),(-1,0)}, f1 -> {(-1,1),(0,-1)}, f2 -> {(0,0), pad(A=0)}
        const char* h1b = (const char*)s_h1 + plane * (PLDW * 4);
        const char* a0 = h1b + (E0 - H1W - 1 + tqh) * 8;
        const char* a1 = h1b + (E0 + (tqh ? -1 : -(H1W - 1))) * 8;
        const char* a2 = h1b + E0 * 8;                   // tqh=1 reads real px (zero A-side)
        // lane (n, quad) stores row ty0 + s*8 + g*4 + quad, col x0 + n
        float* sbase = out + ((img * IMG_H) + ty0 + s * 8 + quad) * IMG_W + x0 + n;

#pragma unroll
        for (int g = 0; g < 2; ++g) {                    // 2 groups of 4 rows
            float sv0, sv1, sv2, sv3;
#pragma unroll
            for (int q = 0; q < 4; ++q) {                // k = g*4+q; row step = 66 px = 528 B
                const int k = g * 4 + q;
                floatx4 acc = bias2;
                acc = __builtin_amdgcn_mfma_f32_16x16x32_fp8_fp8(w2f0, *(const long*)(a0 + k * 528), acc, 0, 0, 0);
                acc = __builtin_amdgcn_mfma_f32_16x16x32_fp8_fp8(w2f1, *(const long*)(a1 + k * 528), acc, 0, 0, 0);
                acc = __builtin_amdgcn_mfma_f32_16x16x32_fp8_fp8(w2f2, *(const long*)(a2 + k * 528), acc, 0, 0, 0);
                float sacc = fmaxf(acc[0], 0.f) * w3q[0];
                sacc = fmaf(fmaxf(acc[1], 0.f), w3q[1], sacc);
                sacc = fmaf(fmaxf(acc[2], 0.f), w3q[2], sacc);
                sacc = fmaf(fmaxf(acc[3], 0.f), w3q[3], sacc);
                sacc += __shfl_xor(sacc, 16);
                sacc += __shfl_xor(sacc, 32);            // full 16-ch sum, replicated in all quads
                if      (q == 0) sv0 = sacc;
                else if (q == 1) sv1 = sacc;
                else if (q == 2) sv2 = sacc;
                else             sv3 = sacc;
            }
            // each lane picks the k matching its quad -> full-wave sigmoid + unmasked store
            float t01 = (quad & 1) ? sv1 : sv0;
            float t23 = (quad & 1) ? sv3 : sv2;
            float v   = (quad & 2) ? t23 : t01;
            float r = __builtin_amdgcn_rcpf(1.f + __expf(-(v + bias3)));
            *(float*)((char*)sbase + g * 1024) = r;      // +4 rows per group
        }
    }
}

extern "C" void kernel_launch(void* const* d_in, const int* in_sizes, int n_in,
                              void* d_out, int out_size, void* d_ws, size_t ws_size,
                              hipStream_t stream) {
    const float* x  = (const float*)d_in[0];
    const float* w1 = (const float*)d_in[1];
    const float* b1 = (const float*)d_in[2];
    const float* w2 = (const float*)d_in[3];
    const float* b2 = (const float*)d_in[4];
    const float* w3 = (const float*)d_in[5];
    const float* b3 = (const float*)d_in[6];
    float* out = (float*)d_out;

    dim3 grid(4, 1024);   // 4 16-row strips per image, 1024 images
    dim3 block(512);
    hipLaunchKernelGGL(pixelcnn_mfma16, grid, block, 0, stream,
                       x, w1, b1, w2, b2, w3, b3, out);
}